// Round 4
// baseline (296.556 us; speedup 1.0000x reference)
//
#include <hip/hip_runtime.h>
#include <hip/hip_bf16.h>

// Problem constants
constexpr int Bsz = 2048;   // batch
constexpr int Iin = 6156;   // input features (= K = N of the big GEMM)
constexpr int IF  = 6159;   // I + O (fin_w row length)
constexpr int Kp  = 6208;   // K padded to multiple of 64 (97 * 64)
constexpr int NpW = 6272;   // w rows stored in ws (multiple of 128)
constexpr int BK  = 32;     // GEMM K-step
constexpr int NT  = Kp / BK;             // 194 K-tiles (even)
constexpr int MT  = Bsz / 256;           // 8 M-tiles
constexpr int NTN = 25;                  // N-tiles of 256 (cols 6272..6399 virtual zeros)

typedef __attribute__((ext_vector_type(8))) short short8;
typedef __attribute__((ext_vector_type(4))) float f32x4;

#define AS1 __attribute__((address_space(1)))
#define AS3 __attribute__((address_space(3)))

__device__ __forceinline__ short f2bf(float f) {
    union { float f; unsigned u; } v; v.f = f;
    unsigned r = v.u + 0x7FFFu + ((v.u >> 16) & 1u);   // RNE
    return (short)(r >> 16);
}

__device__ __forceinline__ short8 pack8(float4 a, float4 b) {
    short8 r;
    r[0] = f2bf(a.x); r[1] = f2bf(a.y); r[2] = f2bf(a.z); r[3] = f2bf(a.w);
    r[4] = f2bf(b.x); r[5] = f2bf(b.y); r[6] = f2bf(b.z); r[7] = f2bf(b.w);
    return r;
}

__device__ __forceinline__ void stage_chunk(const short* src, const short* ldsbase) {
    __builtin_amdgcn_global_load_lds((const AS1 void*)src, (AS3 void*)ldsbase, 16, 0, 0);
}

// ---------------------------------------------------------------------------
// Kernel 1: linear path + bias; fully initializes d_out.
// ---------------------------------------------------------------------------
__global__ void linear_init_kernel(const float* __restrict__ x,
                                   const float* __restrict__ lin_w,
                                   const float* __restrict__ lin_b,
                                   const float* __restrict__ fin_w,
                                   const float* __restrict__ fin_b,
                                   float* __restrict__ out) {
    int wid  = threadIdx.x >> 6;
    int lane = threadIdx.x & 63;
    int b = blockIdx.x * 4 + wid;
    if (b >= Bsz) return;
    const float4* xr = (const float4*)(x + (size_t)b * Iin);
    const float4* w0 = (const float4*)(lin_w);
    const float4* w1 = (const float4*)(lin_w + Iin);
    const float4* w2 = (const float4*)(lin_w + 2 * Iin);
    float s0 = 0.f, s1 = 0.f, s2 = 0.f;
    for (int i = lane; i < Iin / 4; i += 64) {
        float4 xv = xr[i];
        float4 a0 = w0[i], a1 = w1[i], a2 = w2[i];
        s0 += xv.x * a0.x + xv.y * a0.y + xv.z * a0.z + xv.w * a0.w;
        s1 += xv.x * a1.x + xv.y * a1.y + xv.z * a1.z + xv.w * a1.w;
        s2 += xv.x * a2.x + xv.y * a2.y + xv.z * a2.z + xv.w * a2.w;
    }
    #pragma unroll
    for (int off = 1; off < 64; off <<= 1) {
        s0 += __shfl_xor(s0, off, 64);
        s1 += __shfl_xor(s1, off, 64);
        s2 += __shfl_xor(s2, off, 64);
    }
    if (lane == 0) {
        float l0 = s0 + lin_b[0], l1 = s1 + lin_b[1], l2 = s2 + lin_b[2];
        #pragma unroll
        for (int o = 0; o < 3; ++o) {
            out[b * 3 + o] = fin_b[o]
                + fin_w[(size_t)o * IF + 0] * l0
                + fin_w[(size_t)o * IF + 1] * l1
                + fin_w[(size_t)o * IF + 2] * l2;
        }
    }
}

// ---------------------------------------------------------------------------
// Kernel 2: f32 -> bf16 conversion, zero padding, + segment XOR swizzle for
// BK=32 rows: within each 4-slot (32-col) block, ws slot sub holds source
// segment sub ^ ((r>>1)&3).  (rows r, r+8 share a slot -> free 2-way on read)
// ---------------------------------------------------------------------------
__global__ void convert_kernel(const float* __restrict__ src,
                               short* __restrict__ dst,
                               int rows, int src_rows) {
    const int segs = Kp / 8;   // 776
    int total = rows * segs;
    for (int c = blockIdx.x * blockDim.x + threadIdx.x; c < total;
         c += gridDim.x * blockDim.x) {
        int r     = c / segs;
        int s_dst = c - r * segs;
        int blk   = s_dst >> 2;
        int sub   = s_dst & 3;
        int src_col = (blk << 5) + ((sub ^ ((r >> 1) & 3)) << 3);
        short8 st;
        if (r < src_rows && src_col + 8 <= Iin) {
            const float* s = src + (size_t)r * Iin + src_col;
            float4 f0 = *(const float4*)s;
            float4 f1 = *(const float4*)(s + 4);
            st = pack8(f0, f1);
        } else if (r < src_rows && src_col < Iin) {
            const float* s = src + (size_t)r * Iin + src_col;
            #pragma unroll
            for (int e = 0; e < 8; ++e) {
                float v = (src_col + e < Iin) ? s[e] : 0.f;
                st[e] = f2bf(v);
            }
        } else {
            #pragma unroll
            for (int e = 0; e < 8; ++e) st[e] = 0;
        }
        *(short8*)&dst[(size_t)r * Kp + (size_t)s_dst * 8] = st;
    }
}

// ---------------------------------------------------------------------------
// Kernel 3: 8-phase 256x256 GEMM z = x @ w_int^T (bf16 MFMA) + epilogue.
// 8 waves (2M x 4N), wave-tile 128x64 (M_rep=8, N_rep=4). BK=32.
// 4-slot LDS ring (tile t -> slot t&3); stage tiles t+2/t+3 while computing
// t/t+1; counted vmcnt(4) at P2/P4 ends (never drains to 0 in the loop).
// ---------------------------------------------------------------------------
__global__ __launch_bounds__(512, 2) void gemm8p(
    const short* __restrict__ xb, const short* __restrict__ wb,
    const float* __restrict__ xf, const float* __restrict__ finw,
    float* __restrict__ out) {

    __shared__ short lsA[4][8192];   // [slot][256 rows x 32 cols]
    __shared__ short lsB[4][8192];
    __shared__ float part[256][3];

    const int tid  = threadIdx.x;
    const int lane = tid & 63;
    const int wid  = tid >> 6;       // 0..7
    const int wr   = wid >> 2;       // 0..1  (M half)
    const int wc   = wid & 3;        // 0..3  (N quarter)
    const int l15  = lane & 15;
    const int koff = (((lane >> 4) ^ ((lane >> 1) & 3)) << 3);  // swizzled k-slot

    // bijective XCD swizzle: 200 blocks = 8 XCDs x 25
    int swz = ((int)blockIdx.x & 7) * NTN + ((int)blockIdx.x >> 3);
    int tm = swz & 7;
    int tn = swz >> 3;
    int bm0 = tm << 8;
    int in0 = tn << 8;

    const int srow = lane >> 2;      // staging: row within 16-row wave chunk
    const int ssl  = lane & 3;       // staging: 16B slot within row
    const short* zptr = wb + 6176;   // 16 B of guaranteed zeros (row 0, cols>=Iin)

    f32x4 acc[8][4];
    #pragma unroll
    for (int m = 0; m < 8; ++m)
        #pragma unroll
        for (int n = 0; n < 4; ++n)
            acc[m][n] = (f32x4){0.f, 0.f, 0.f, 0.f};

    auto stageA = [&](int tk, int h) {
        int row = h * 128 + wid * 16 + srow;
        const short* src = xb + (size_t)(bm0 + row) * Kp + tk * 32 + ssl * 8;
        stage_chunk(src, &lsA[tk & 3][(h * 128 + wid * 16) * 32]);
    };
    auto stageB = [&](int tk, int h) {
        int row = h * 128 + wid * 16 + srow;
        int rg  = in0 + row;
        const short* src = (rg < NpW)
            ? wb + (size_t)rg * Kp + tk * 32 + ssl * 8 : zptr;
        stage_chunk(src, &lsB[tk & 3][(h * 128 + wid * 16) * 32]);
    };
    auto ldA = [&](int slot, int m) -> short8 {
        return *(const short8*)&lsA[slot][(wr * 128 + m * 16 + l15) * 32 + koff];
    };
    auto ldB = [&](int slot, int n) -> short8 {
        return *(const short8*)&lsB[slot][(wc * 64 + n * 16 + l15) * 32 + koff];
    };

    // prologue: stage tiles 0 and 1 (4 loads each per thread)
    stageA(0, 0); stageA(0, 1); stageB(0, 0); stageB(0, 1);
    stageA(1, 0); stageA(1, 1); stageB(1, 0); stageB(1, 1);
    asm volatile("s_waitcnt vmcnt(4)" ::: "memory");   // tile 0 landed
    __builtin_amdgcn_s_barrier();

    short8 Bf[4], Af[4];

    for (int i = 0; i < NT / 2; ++i) {
        int a = 2 * i, b = a + 1;
        int sa = (a + 2 < NT) ? a + 2 : a - 2;   // same slot either way
        int sb = (b + 2 < NT) ? b + 2 : b - 2;
        int sA = a & 3, sB = b & 3;

        // ---- P1: tile a, m 0..3 (loads B frags for the tile)
        #pragma unroll
        for (int n = 0; n < 4; ++n) Bf[n] = ldB(sA, n);
        #pragma unroll
        for (int m = 0; m < 4; ++m) Af[m] = ldA(sA, m);
        __builtin_amdgcn_sched_barrier(0);
        stageA(sa, 0); stageA(sa, 1);
        __builtin_amdgcn_s_barrier();
        asm volatile("s_waitcnt lgkmcnt(0)" ::: "memory");
        __builtin_amdgcn_sched_barrier(0);
        __builtin_amdgcn_s_setprio(1);
        #pragma unroll
        for (int m = 0; m < 4; ++m)
            #pragma unroll
            for (int n = 0; n < 4; ++n)
                acc[m][n] = __builtin_amdgcn_mfma_f32_16x16x32_bf16(
                    Af[m], Bf[n], acc[m][n], 0, 0, 0);
        __builtin_amdgcn_s_setprio(0);
        __builtin_amdgcn_s_barrier();

        // ---- P2: tile a, m 4..7
        #pragma unroll
        for (int m = 0; m < 4; ++m) Af[m] = ldA(sA, m + 4);
        __builtin_amdgcn_sched_barrier(0);
        stageB(sa, 0); stageB(sa, 1);
        __builtin_amdgcn_s_barrier();
        asm volatile("s_waitcnt lgkmcnt(0)" ::: "memory");
        __builtin_amdgcn_sched_barrier(0);
        __builtin_amdgcn_s_setprio(1);
        #pragma unroll
        for (int m = 0; m < 4; ++m)
            #pragma unroll
            for (int n = 0; n < 4; ++n)
                acc[m + 4][n] = __builtin_amdgcn_mfma_f32_16x16x32_bf16(
                    Af[m], Bf[n], acc[m + 4][n], 0, 0, 0);
        __builtin_amdgcn_s_setprio(0);
        asm volatile("s_waitcnt vmcnt(4)" ::: "memory");   // tile b landed
        __builtin_amdgcn_s_barrier();

        // ---- P3: tile b, m 0..3
        #pragma unroll
        for (int n = 0; n < 4; ++n) Bf[n] = ldB(sB, n);
        #pragma unroll
        for (int m = 0; m < 4; ++m) Af[m] = ldA(sB, m);
        __builtin_amdgcn_sched_barrier(0);
        stageA(sb, 0); stageA(sb, 1);
        __builtin_amdgcn_s_barrier();
        asm volatile("s_waitcnt lgkmcnt(0)" ::: "memory");
        __builtin_amdgcn_sched_barrier(0);
        __builtin_amdgcn_s_setprio(1);
        #pragma unroll
        for (int m = 0; m < 4; ++m)
            #pragma unroll
            for (int n = 0; n < 4; ++n)
                acc[m][n] = __builtin_amdgcn_mfma_f32_16x16x32_bf16(
                    Af[m], Bf[n], acc[m][n], 0, 0, 0);
        __builtin_amdgcn_s_setprio(0);
        __builtin_amdgcn_s_barrier();

        // ---- P4: tile b, m 4..7
        #pragma unroll
        for (int m = 0; m < 4; ++m) Af[m] = ldA(sB, m + 4);
        __builtin_amdgcn_sched_barrier(0);
        stageB(sb, 0); stageB(sb, 1);
        __builtin_amdgcn_s_barrier();
        asm volatile("s_waitcnt lgkmcnt(0)" ::: "memory");
        __builtin_amdgcn_sched_barrier(0);
        __builtin_amdgcn_s_setprio(1);
        #pragma unroll
        for (int m = 0; m < 4; ++m)
            #pragma unroll
            for (int n = 0; n < 4; ++n)
                acc[m + 4][n] = __builtin_amdgcn_mfma_f32_16x16x32_bf16(
                    Af[m], Bf[n], acc[m + 4][n], 0, 0, 0);
        __builtin_amdgcn_s_setprio(0);
        asm volatile("s_waitcnt vmcnt(4)" ::: "memory");   // tile a+2 landed
        __builtin_amdgcn_s_barrier();
    }

    // ---- epilogue: out[b,o] += sum_gi finw[o,3+gi] * x[b,gi] * z[b,gi]
    __syncthreads();   // drains everything (incl. tail dummy stages)
    for (int t = tid; t < 768; t += 512) ((float*)part)[t] = 0.f;
    __syncthreads();

    int q4 = lane >> 4;
    #pragma unroll
    for (int m = 0; m < 8; ++m) {
        #pragma unroll
        for (int r = 0; r < 4; ++r) {
            int lr = wr * 128 + m * 16 + q4 * 4 + r;   // 0..255
            int bg = bm0 + lr;
            float s0 = 0.f, s1 = 0.f, s2 = 0.f;
            #pragma unroll
            for (int n = 0; n < 4; ++n) {
                int gi = in0 + wc * 64 + n * 16 + l15;
                if (gi < Iin) {
                    float inter = acc[m][n][r] * xf[(size_t)bg * Iin + gi];
                    s0 += inter * finw[(size_t)0 * IF + 3 + gi];
                    s1 += inter * finw[(size_t)1 * IF + 3 + gi];
                    s2 += inter * finw[(size_t)2 * IF + 3 + gi];
                }
            }
            #pragma unroll
            for (int off = 1; off < 16; off <<= 1) {
                s0 += __shfl_xor(s0, off, 64);
                s1 += __shfl_xor(s1, off, 64);
                s2 += __shfl_xor(s2, off, 64);
            }
            if (l15 == 0) {
                atomicAdd(&part[lr][0], s0);
                atomicAdd(&part[lr][1], s1);
                atomicAdd(&part[lr][2], s2);
            }
        }
    }
    __syncthreads();
    for (int t = tid; t < 768; t += 512) {
        int lr = t / 3, o = t - lr * 3;
        atomicAdd(&out[(size_t)(bm0 + lr) * 3 + o], part[lr][o]);
    }
}

// ---------------------------------------------------------------------------
// Fallback (no workspace): self-staged 2-barrier kernel (mask-7 swizzle).
// ---------------------------------------------------------------------------
__global__ __launch_bounds__(256) void gemm_fallback(
    const float* __restrict__ xf, const float* __restrict__ wf,
    const float* __restrict__ finw, float* __restrict__ out) {

    __shared__ short lsA[128 * 64];
    __shared__ short lsB[128 * 64];
    __shared__ float part[128][3];

    int tid  = threadIdx.x;
    int lane = tid & 63;
    int wid  = tid >> 6;
    int wm   = wid & 1;
    int wn   = wid >> 1;

    int ntiles = (Bsz / 128) * (NpW / 128);
    int tile = (blockIdx.x & 7) * (ntiles >> 3) + (blockIdx.x >> 3);
    int tm = tile & 15;
    int tn = tile >> 4;
    int bm0 = tm << 7;
    int in0 = tn << 7;

    f32x4 acc[4][4];
    #pragma unroll
    for (int m = 0; m < 4; ++m)
        #pragma unroll
        for (int n = 0; n < 4; ++n)
            acc[m][n] = (f32x4){0.f, 0.f, 0.f, 0.f};

    for (int k0 = 0; k0 < Kp; k0 += 64) {
        #pragma unroll
        for (int it = 0; it < 4; ++it) {
            int idx = it * 256 + tid;
            int r   = idx >> 3;
            int seg = idx & 7;
            int kc  = k0 + seg * 8;
            int sd  = (seg ^ (r & 7)) << 3;
            {
                const float* s = xf + (size_t)(bm0 + r) * Iin + kc;
                short8 st;
                if (kc + 8 <= Iin) {
                    float4 f0 = *(const float4*)s;
                    float4 f1 = *(const float4*)(s + 4);
                    st = pack8(f0, f1);
                } else {
                    #pragma unroll
                    for (int e = 0; e < 8; ++e) {
                        float v = (kc + e < Iin) ? s[e] : 0.f;
                        st[e] = f2bf(v);
                    }
                }
                *(short8*)&lsA[r * 64 + sd] = st;
            }
            {
                int grow = in0 + r;
                short8 st;
                if (grow < Iin && kc + 8 <= Iin) {
                    const float* s = wf + (size_t)grow * Iin + kc;
                    float4 f0 = *(const float4*)s;
                    float4 f1 = *(const float4*)(s + 4);
                    st = pack8(f0, f1);
                } else if (grow < Iin) {
                    const float* s = wf + (size_t)grow * Iin + kc;
                    #pragma unroll
                    for (int e = 0; e < 8; ++e) {
                        float v = (kc + e < Iin) ? s[e] : 0.f;
                        st[e] = f2bf(v);
                    }
                } else {
                    #pragma unroll
                    for (int e = 0; e < 8; ++e) st[e] = 0;
                }
                *(short8*)&lsB[r * 64 + sd] = st;
            }
        }
        __syncthreads();

        #pragma unroll
        for (int kk = 0; kk < 2; ++kk) {
            int q = (kk << 2) + (lane >> 4);
            short8 af[4], bfr[4];
            #pragma unroll
            for (int m = 0; m < 4; ++m) {
                int R = wm * 64 + m * 16 + (lane & 15);
                af[m] = *(const short8*)&lsA[R * 64 + ((q ^ (R & 7)) << 3)];
            }
            #pragma unroll
            for (int n = 0; n < 4; ++n) {
                int R = wn * 64 + n * 16 + (lane & 15);
                bfr[n] = *(const short8*)&lsB[R * 64 + ((q ^ (R & 7)) << 3)];
            }
            #pragma unroll
            for (int m = 0; m < 4; ++m)
                #pragma unroll
                for (int n = 0; n < 4; ++n)
                    acc[m][n] = __builtin_amdgcn_mfma_f32_16x16x32_bf16(
                        af[m], bfr[n], acc[m][n], 0, 0, 0);
        }
        __syncthreads();
    }

    for (int t = tid; t < 384; t += 256) ((float*)part)[t] = 0.f;
    __syncthreads();

    #pragma unroll
    for (int m = 0; m < 4; ++m) {
        int rowbase = bm0 + wm * 64 + m * 16 + ((lane >> 4) << 2);
        #pragma unroll
        for (int r = 0; r < 4; ++r) {
            int b = rowbase + r;
            float s0 = 0.f, s1 = 0.f, s2 = 0.f;
            #pragma unroll
            for (int n = 0; n < 4; ++n) {
                int gi = in0 + wn * 64 + n * 16 + (lane & 15);
                if (gi < Iin) {
                    float inter = acc[m][n][r] * xf[(size_t)b * Iin + gi];
                    s0 += inter * finw[(size_t)0 * IF + 3 + gi];
                    s1 += inter * finw[(size_t)1 * IF + 3 + gi];
                    s2 += inter * finw[(size_t)2 * IF + 3 + gi];
                }
            }
            #pragma unroll
            for (int off = 1; off < 16; off <<= 1) {
                s0 += __shfl_xor(s0, off, 64);
                s1 += __shfl_xor(s1, off, 64);
                s2 += __shfl_xor(s2, off, 64);
            }
            if ((lane & 15) == 0) {
                int lr = b - bm0;
                atomicAdd(&part[lr][0], s0);
                atomicAdd(&part[lr][1], s1);
                atomicAdd(&part[lr][2], s2);
            }
        }
    }
    __syncthreads();
    for (int t = tid; t < 384; t += 256) {
        int lr = t / 3, o = t - lr * 3;
        atomicAdd(&out[(size_t)(bm0 + lr) * 3 + o], part[lr][o]);
    }
}

// ---------------------------------------------------------------------------
extern "C" void kernel_launch(void* const* d_in, const int* in_sizes, int n_in,
                              void* d_out, int out_size, void* d_ws, size_t ws_size,
                              hipStream_t stream) {
    const float* x     = (const float*)d_in[0];
    const float* lin_w = (const float*)d_in[1];
    const float* lin_b = (const float*)d_in[2];
    const float* w_int = (const float*)d_in[3];
    const float* fin_w = (const float*)d_in[4];
    const float* fin_b = (const float*)d_in[5];
    float* out = (float*)d_out;

    linear_init_kernel<<<Bsz / 4, 256, 0, stream>>>(x, lin_w, lin_b, fin_w, fin_b, out);

    const size_t xb_elems = (size_t)Bsz * Kp;    // 12,713,984
    const size_t wb_elems = (size_t)NpW * Kp;    // 38,936,576
    const size_t need = (xb_elems + wb_elems) * sizeof(short);   // 103.3 MB

    if (ws_size >= need) {
        short* xb = (short*)d_ws;
        short* wb = xb + xb_elems;
        convert_kernel<<<2048, 256, 0, stream>>>(x, xb, Bsz, Bsz);
        convert_kernel<<<2048, 256, 0, stream>>>(w_int, wb, NpW, Iin);
        gemm8p<<<MT * NTN, 512, 0, stream>>>(xb, wb, x, fin_w, out);
    } else {
        const int ntiles = (Bsz / 128) * (NpW / 128);
        gemm_fallback<<<ntiles, 256, 0, stream>>>(x, w_int, fin_w, out);
    }
}

// Round 5
// 277.004 us; speedup vs baseline: 1.0706x; 1.0706x over previous
//
#include <hip/hip_runtime.h>
#include <hip/hip_bf16.h>

// Problem constants
constexpr int Bsz = 2048;   // batch
constexpr int Iin = 6156;   // input features (= K = N of the big GEMM)
constexpr int IF  = 6159;   // I + O (fin_w row length)
constexpr int Kp  = 6208;   // K padded to multiple of 64 (97 * 64)
constexpr int NpW = 6272;   // w rows stored in ws (multiple of 128)
constexpr int NT  = Kp / 32;             // 194 K-tiles (BK=32)
constexpr int MT  = Bsz / 256;           // 8 M-tiles
constexpr int NTN = 25;                  // N-tiles of 256 (cols 6272..6399 virtual zeros)

typedef __attribute__((ext_vector_type(8))) short short8;
typedef __attribute__((ext_vector_type(4))) float f32x4;

#define AS1 __attribute__((address_space(1)))
#define AS3 __attribute__((address_space(3)))

__device__ __forceinline__ short f2bf(float f) {
    union { float f; unsigned u; } v; v.f = f;
    unsigned r = v.u + 0x7FFFu + ((v.u >> 16) & 1u);   // RNE
    return (short)(r >> 16);
}

__device__ __forceinline__ short8 pack8(float4 a, float4 b) {
    short8 r;
    r[0] = f2bf(a.x); r[1] = f2bf(a.y); r[2] = f2bf(a.z); r[3] = f2bf(a.w);
    r[4] = f2bf(b.x); r[5] = f2bf(b.y); r[6] = f2bf(b.z); r[7] = f2bf(b.w);
    return r;
}

__device__ __forceinline__ void stage_chunk(const short* src, const short* ldsbase) {
    __builtin_amdgcn_global_load_lds((const AS1 void*)src, (AS3 void*)ldsbase, 16, 0, 0);
}

// ---------------------------------------------------------------------------
// Kernel 1: linear path + bias; fully initializes d_out.
// ---------------------------------------------------------------------------
__global__ void linear_init_kernel(const float* __restrict__ x,
                                   const float* __restrict__ lin_w,
                                   const float* __restrict__ lin_b,
                                   const float* __restrict__ fin_w,
                                   const float* __restrict__ fin_b,
                                   float* __restrict__ out) {
    int wid  = threadIdx.x >> 6;
    int lane = threadIdx.x & 63;
    int b = blockIdx.x * 4 + wid;
    if (b >= Bsz) return;
    const float4* xr = (const float4*)(x + (size_t)b * Iin);
    const float4* w0 = (const float4*)(lin_w);
    const float4* w1 = (const float4*)(lin_w + Iin);
    const float4* w2 = (const float4*)(lin_w + 2 * Iin);
    float s0 = 0.f, s1 = 0.f, s2 = 0.f;
    for (int i = lane; i < Iin / 4; i += 64) {
        float4 xv = xr[i];
        float4 a0 = w0[i], a1 = w1[i], a2 = w2[i];
        s0 += xv.x * a0.x + xv.y * a0.y + xv.z * a0.z + xv.w * a0.w;
        s1 += xv.x * a1.x + xv.y * a1.y + xv.z * a1.z + xv.w * a1.w;
        s2 += xv.x * a2.x + xv.y * a2.y + xv.z * a2.z + xv.w * a2.w;
    }
    #pragma unroll
    for (int off = 1; off < 64; off <<= 1) {
        s0 += __shfl_xor(s0, off, 64);
        s1 += __shfl_xor(s1, off, 64);
        s2 += __shfl_xor(s2, off, 64);
    }
    if (lane == 0) {
        float l0 = s0 + lin_b[0], l1 = s1 + lin_b[1], l2 = s2 + lin_b[2];
        #pragma unroll
        for (int o = 0; o < 3; ++o) {
            out[b * 3 + o] = fin_b[o]
                + fin_w[(size_t)o * IF + 0] * l0
                + fin_w[(size_t)o * IF + 1] * l1
                + fin_w[(size_t)o * IF + 2] * l2;
        }
    }
}

// ---------------------------------------------------------------------------
// Kernel 2: f32 -> bf16 conversion, zero padding, + segment XOR swizzle for
// BK=32 rows: within each 4-slot (32-col) block, ws slot sub holds source
// segment sub ^ ((r>>1)&3).
// ---------------------------------------------------------------------------
__global__ void convert_kernel(const float* __restrict__ src,
                               short* __restrict__ dst,
                               int rows, int src_rows) {
    const int segs = Kp / 8;   // 776
    int total = rows * segs;
    for (int c = blockIdx.x * blockDim.x + threadIdx.x; c < total;
         c += gridDim.x * blockDim.x) {
        int r     = c / segs;
        int s_dst = c - r * segs;
        int blk   = s_dst >> 2;
        int sub   = s_dst & 3;
        int src_col = (blk << 5) + ((sub ^ ((r >> 1) & 3)) << 3);
        short8 st;
        if (r < src_rows && src_col + 8 <= Iin) {
            const float* s = src + (size_t)r * Iin + src_col;
            float4 f0 = *(const float4*)s;
            float4 f1 = *(const float4*)(s + 4);
            st = pack8(f0, f1);
        } else if (r < src_rows && src_col < Iin) {
            const float* s = src + (size_t)r * Iin + src_col;
            #pragma unroll
            for (int e = 0; e < 8; ++e) {
                float v = (src_col + e < Iin) ? s[e] : 0.f;
                st[e] = f2bf(v);
            }
        } else {
            #pragma unroll
            for (int e = 0; e < 8; ++e) st[e] = 0;
        }
        *(short8*)&dst[(size_t)r * Kp + (size_t)s_dst * 8] = st;
    }
}

// ---------------------------------------------------------------------------
// Kernel 3: 256x256 GEMM z = x @ w_int^T (bf16 MFMA) + interaction epilogue.
// 8 waves (2M x 4N), wave-tile 128x64 (M_rep=8, N_rep=4). BK=32.
// ONE barrier per K-tile. 4-slot LDS ring, stage-ahead-2, counted vmcnt(4).
// Chunked lgkmcnt: af4-7 drain under the first 16 MFMA.
// ---------------------------------------------------------------------------
__global__ __launch_bounds__(512, 2) void gemm1b(
    const short* __restrict__ xb, const short* __restrict__ wb,
    const float* __restrict__ xf, const float* __restrict__ finw,
    float* __restrict__ out) {

    __shared__ short lsA[4][8192];   // [slot][256 rows x 32 cols]
    __shared__ short lsB[4][8192];
    __shared__ float part[256][3];

    const int tid  = threadIdx.x;
    const int lane = tid & 63;
    const int wid  = tid >> 6;       // 0..7
    const int wr   = wid >> 2;       // 0..1  (M half)
    const int wc   = wid & 3;        // 0..3  (N quarter)
    const int l15  = lane & 15;
    const int koff = (((lane >> 4) ^ ((lane >> 1) & 3)) << 3);  // swizzled k-slot

    // bijective XCD swizzle: 200 blocks = 8 XCDs x 25
    int swz = ((int)blockIdx.x & 7) * NTN + ((int)blockIdx.x >> 3);
    int tm = swz & 7;
    int tn = swz >> 3;
    int bm0 = tm << 8;
    int in0 = tn << 8;

    const int srow = lane >> 2;      // staging: row within 16-row wave chunk
    const int ssl  = lane & 3;       // staging: 16B slot within row
    const short* zptr = wb + 6176;   // 16 B of guaranteed zeros (row 0, cols>=Iin)

    f32x4 acc[8][4];
    #pragma unroll
    for (int m = 0; m < 8; ++m)
        #pragma unroll
        for (int n = 0; n < 4; ++n)
            acc[m][n] = (f32x4){0.f, 0.f, 0.f, 0.f};

    auto stageA = [&](int tk, int h) {
        int row = h * 128 + wid * 16 + srow;
        const short* src = xb + (size_t)(bm0 + row) * Kp + tk * 32 + ssl * 8;
        stage_chunk(src, &lsA[tk & 3][(h * 128 + wid * 16) * 32]);
    };
    auto stageB = [&](int tk, int h) {
        int row = h * 128 + wid * 16 + srow;
        int rg  = in0 + row;
        const short* src = (rg < NpW)
            ? wb + (size_t)rg * Kp + tk * 32 + ssl * 8 : zptr;
        stage_chunk(src, &lsB[tk & 3][(h * 128 + wid * 16) * 32]);
    };
    auto ldA = [&](int slot, int m) -> short8 {
        return *(const short8*)&lsA[slot][(wr * 128 + m * 16 + l15) * 32 + koff];
    };
    auto ldB = [&](int slot, int n) -> short8 {
        return *(const short8*)&lsB[slot][(wc * 64 + n * 16 + l15) * 32 + koff];
    };

    // prologue: stage tiles 0 and 1 (4 loads each per thread)
    stageA(0, 0); stageA(0, 1); stageB(0, 0); stageB(0, 1);
    stageA(1, 0); stageA(1, 1); stageB(1, 0); stageB(1, 1);
    asm volatile("s_waitcnt vmcnt(4)" ::: "memory");   // tile 0 landed
    __builtin_amdgcn_s_barrier();

    for (int kt = 0; kt < NT; ++kt) {
        const int slot = kt & 3;
        short8 af[8], bf4[4];

        // group 1: af0-3 + bf0-3 (first 8 lgkm events)
        #pragma unroll
        for (int m = 0; m < 4; ++m) af[m] = ldA(slot, m);
        #pragma unroll
        for (int n = 0; n < 4; ++n) bf4[n] = ldB(slot, n);
        __builtin_amdgcn_sched_barrier(0);
        // group 2: af4-7 (last 4 lgkm events)
        #pragma unroll
        for (int m = 4; m < 8; ++m) af[m] = ldA(slot, m);
        __builtin_amdgcn_sched_barrier(0);

        // stage kt+2 into its ring slot (WAR-safe: last read 2 barriers ago)
        if (kt + 2 < NT) {
            stageA(kt + 2, 0); stageA(kt + 2, 1);
            stageB(kt + 2, 0); stageB(kt + 2, 1);
        }
        __builtin_amdgcn_sched_barrier(0);

        asm volatile("s_waitcnt lgkmcnt(4)" ::: "memory");   // af0-3,bf0-3 ready
        __builtin_amdgcn_sched_barrier(0);
        __builtin_amdgcn_s_setprio(1);
        #pragma unroll
        for (int m = 0; m < 4; ++m)
            #pragma unroll
            for (int n = 0; n < 4; ++n)
                acc[m][n] = __builtin_amdgcn_mfma_f32_16x16x32_bf16(
                    af[m], bf4[n], acc[m][n], 0, 0, 0);
        __builtin_amdgcn_s_setprio(0);
        __builtin_amdgcn_sched_barrier(0);

        asm volatile("s_waitcnt lgkmcnt(0)" ::: "memory");   // af4-7 ready
        __builtin_amdgcn_sched_barrier(0);
        __builtin_amdgcn_s_setprio(1);
        #pragma unroll
        for (int m = 4; m < 8; ++m)
            #pragma unroll
            for (int n = 0; n < 4; ++n)
                acc[m][n] = __builtin_amdgcn_mfma_f32_16x16x32_bf16(
                    af[m], bf4[n], acc[m][n], 0, 0, 0);
        __builtin_amdgcn_s_setprio(0);
        __builtin_amdgcn_sched_barrier(0);

        if (kt < NT - 2)
            asm volatile("s_waitcnt vmcnt(4)" ::: "memory");   // tile kt+1 landed
        else
            asm volatile("s_waitcnt vmcnt(0)" ::: "memory");   // tail drain
        __builtin_amdgcn_s_barrier();
    }

    // ---- epilogue: out[b,o] += sum_gi finw[o,3+gi] * x[b,gi] * z[b,gi]
    __syncthreads();
    for (int t = tid; t < 768; t += 512) ((float*)part)[t] = 0.f;
    __syncthreads();

    int q4 = lane >> 4;
    #pragma unroll
    for (int m = 0; m < 8; ++m) {
        #pragma unroll
        for (int r = 0; r < 4; ++r) {
            int lr = wr * 128 + m * 16 + q4 * 4 + r;   // 0..255
            int bg = bm0 + lr;
            float s0 = 0.f, s1 = 0.f, s2 = 0.f;
            #pragma unroll
            for (int n = 0; n < 4; ++n) {
                int gi = in0 + wc * 64 + n * 16 + l15;
                if (gi < Iin) {
                    float inter = acc[m][n][r] * xf[(size_t)bg * Iin + gi];
                    s0 += inter * finw[(size_t)0 * IF + 3 + gi];
                    s1 += inter * finw[(size_t)1 * IF + 3 + gi];
                    s2 += inter * finw[(size_t)2 * IF + 3 + gi];
                }
            }
            #pragma unroll
            for (int off = 1; off < 16; off <<= 1) {
                s0 += __shfl_xor(s0, off, 64);
                s1 += __shfl_xor(s1, off, 64);
                s2 += __shfl_xor(s2, off, 64);
            }
            if (l15 == 0) {
                atomicAdd(&part[lr][0], s0);
                atomicAdd(&part[lr][1], s1);
                atomicAdd(&part[lr][2], s2);
            }
        }
    }
    __syncthreads();
    for (int t = tid; t < 768; t += 512) {
        int lr = t / 3, o = t - lr * 3;
        atomicAdd(&out[(size_t)(bm0 + lr) * 3 + o], part[lr][o]);
    }
}

// ---------------------------------------------------------------------------
// Fallback (no workspace): self-staged 2-barrier kernel (mask-7 swizzle).
// ---------------------------------------------------------------------------
__global__ __launch_bounds__(256) void gemm_fallback(
    const float* __restrict__ xf, const float* __restrict__ wf,
    const float* __restrict__ finw, float* __restrict__ out) {

    __shared__ short lsA[128 * 64];
    __shared__ short lsB[128 * 64];
    __shared__ float part[128][3];

    int tid  = threadIdx.x;
    int lane = tid & 63;
    int wid  = tid >> 6;
    int wm   = wid & 1;
    int wn   = wid >> 1;

    int ntiles = (Bsz / 128) * (NpW / 128);
    int tile = (blockIdx.x & 7) * (ntiles >> 3) + (blockIdx.x >> 3);
    int tm = tile & 15;
    int tn = tile >> 4;
    int bm0 = tm << 7;
    int in0 = tn << 7;

    f32x4 acc[4][4];
    #pragma unroll
    for (int m = 0; m < 4; ++m)
        #pragma unroll
        for (int n = 0; n < 4; ++n)
            acc[m][n] = (f32x4){0.f, 0.f, 0.f, 0.f};

    for (int k0 = 0; k0 < Kp; k0 += 64) {
        #pragma unroll
        for (int it = 0; it < 4; ++it) {
            int idx = it * 256 + tid;
            int r   = idx >> 3;
            int seg = idx & 7;
            int kc  = k0 + seg * 8;
            int sd  = (seg ^ (r & 7)) << 3;
            {
                const float* s = xf + (size_t)(bm0 + r) * Iin + kc;
                short8 st;
                if (kc + 8 <= Iin) {
                    float4 f0 = *(const float4*)s;
                    float4 f1 = *(const float4*)(s + 4);
                    st = pack8(f0, f1);
                } else {
                    #pragma unroll
                    for (int e = 0; e < 8; ++e) {
                        float v = (kc + e < Iin) ? s[e] : 0.f;
                        st[e] = f2bf(v);
                    }
                }
                *(short8*)&lsA[r * 64 + sd] = st;
            }
            {
                int grow = in0 + r;
                short8 st;
                if (grow < Iin && kc + 8 <= Iin) {
                    const float* s = wf + (size_t)grow * Iin + kc;
                    float4 f0 = *(const float4*)s;
                    float4 f1 = *(const float4*)(s + 4);
                    st = pack8(f0, f1);
                } else if (grow < Iin) {
                    const float* s = wf + (size_t)grow * Iin + kc;
                    #pragma unroll
                    for (int e = 0; e < 8; ++e) {
                        float v = (kc + e < Iin) ? s[e] : 0.f;
                        st[e] = f2bf(v);
                    }
                } else {
                    #pragma unroll
                    for (int e = 0; e < 8; ++e) st[e] = 0;
                }
                *(short8*)&lsB[r * 64 + sd] = st;
            }
        }
        __syncthreads();

        #pragma unroll
        for (int kk = 0; kk < 2; ++kk) {
            int q = (kk << 2) + (lane >> 4);
            short8 af[4], bfr[4];
            #pragma unroll
            for (int m = 0; m < 4; ++m) {
                int R = wm * 64 + m * 16 + (lane & 15);
                af[m] = *(const short8*)&lsA[R * 64 + ((q ^ (R & 7)) << 3)];
            }
            #pragma unroll
            for (int n = 0; n < 4; ++n) {
                int R = wn * 64 + n * 16 + (lane & 15);
                bfr[n] = *(const short8*)&lsB[R * 64 + ((q ^ (R & 7)) << 3)];
            }
            #pragma unroll
            for (int m = 0; m < 4; ++m)
                #pragma unroll
                for (int n = 0; n < 4; ++n)
                    acc[m][n] = __builtin_amdgcn_mfma_f32_16x16x32_bf16(
                        af[m], bfr[n], acc[m][n], 0, 0, 0);
        }
        __syncthreads();
    }

    for (int t = tid; t < 384; t += 256) ((float*)part)[t] = 0.f;
    __syncthreads();

    #pragma unroll
    for (int m = 0; m < 4; ++m) {
        int rowbase = bm0 + wm * 64 + m * 16 + ((lane >> 4) << 2);
        #pragma unroll
        for (int r = 0; r < 4; ++r) {
            int b = rowbase + r;
            float s0 = 0.f, s1 = 0.f, s2 = 0.f;
            #pragma unroll
            for (int n = 0; n < 4; ++n) {
                int gi = in0 + wn * 64 + n * 16 + (lane & 15);
                if (gi < Iin) {
                    float inter = acc[m][n][r] * xf[(size_t)b * Iin + gi];
                    s0 += inter * finw[(size_t)0 * IF + 3 + gi];
                    s1 += inter * finw[(size_t)1 * IF + 3 + gi];
                    s2 += inter * finw[(size_t)2 * IF + 3 + gi];
                }
            }
            #pragma unroll
            for (int off = 1; off < 16; off <<= 1) {
                s0 += __shfl_xor(s0, off, 64);
                s1 += __shfl_xor(s1, off, 64);
                s2 += __shfl_xor(s2, off, 64);
            }
            if ((lane & 15) == 0) {
                int lr = b - bm0;
                atomicAdd(&part[lr][0], s0);
                atomicAdd(&part[lr][1], s1);
                atomicAdd(&part[lr][2], s2);
            }
        }
    }
    __syncthreads();
    for (int t = tid; t < 384; t += 256) {
        int lr = t / 3, o = t - lr * 3;
        atomicAdd(&out[(size_t)(bm0 + lr) * 3 + o], part[lr][o]);
    }
}

// ---------------------------------------------------------------------------
extern "C" void kernel_launch(void* const* d_in, const int* in_sizes, int n_in,
                              void* d_out, int out_size, void* d_ws, size_t ws_size,
                              hipStream_t stream) {
    const float* x     = (const float*)d_in[0];
    const float* lin_w = (const float*)d_in[1];
    const float* lin_b = (const float*)d_in[2];
    const float* w_int = (const float*)d_in[3];
    const float* fin_w = (const float*)d_in[4];
    const float* fin_b = (const float*)d_in[5];
    float* out = (float*)d_out;

    linear_init_kernel<<<Bsz / 4, 256, 0, stream>>>(x, lin_w, lin_b, fin_w, fin_b, out);

    const size_t xb_elems = (size_t)Bsz * Kp;    // 12,713,984
    const size_t wb_elems = (size_t)NpW * Kp;    // 38,936,576
    const size_t need = (xb_elems + wb_elems) * sizeof(short);   // 103.3 MB

    if (ws_size >= need) {
        short* xb = (short*)d_ws;
        short* wb = xb + xb_elems;
        convert_kernel<<<2048, 256, 0, stream>>>(x, xb, Bsz, Bsz);
        convert_kernel<<<2048, 256, 0, stream>>>(w_int, wb, NpW, Iin);
        gemm1b<<<MT * NTN, 512, 0, stream>>>(xb, wb, x, fin_w, out);
    } else {
        const int ntiles = (Bsz / 128) * (NpW / 128);
        gemm_fallback<<<ntiles, 256, 0, stream>>>(x, w_int, fin_w, out);
    }
}

// Round 6
// 257.284 us; speedup vs baseline: 1.1526x; 1.0766x over previous
//
#include <hip/hip_runtime.h>
#include <hip/hip_bf16.h>

// Problem constants
constexpr int Bsz = 2048;   // batch
constexpr int Iin = 6156;   // input features (= K = N of the big GEMM)
constexpr int IF  = 6159;   // I + O (fin_w row length)
constexpr int Kp  = 6208;   // K padded to multiple of 64 (97 * 64)
constexpr int NpW = 6272;   // w rows stored in ws (multiple of 128)
constexpr int NT  = Kp / 32;             // 194 K-tiles (BK=32)
constexpr int MT  = Bsz / 256;           // 8 M-tiles
constexpr int NTN = 25;                  // N-tiles of 256 (cols 6272..6399 virtual zeros)

typedef __attribute__((ext_vector_type(8))) short short8;
typedef __attribute__((ext_vector_type(4))) float f32x4;

#define AS1 __attribute__((address_space(1)))
#define AS3 __attribute__((address_space(3)))

__device__ __forceinline__ short f2bf(float f) {
    union { float f; unsigned u; } v; v.f = f;
    unsigned r = v.u + 0x7FFFu + ((v.u >> 16) & 1u);   // RNE
    return (short)(r >> 16);
}

__device__ __forceinline__ short8 pack8(float4 a, float4 b) {
    short8 r;
    r[0] = f2bf(a.x); r[1] = f2bf(a.y); r[2] = f2bf(a.z); r[3] = f2bf(a.w);
    r[4] = f2bf(b.x); r[5] = f2bf(b.y); r[6] = f2bf(b.z); r[7] = f2bf(b.w);
    return r;
}

__device__ __forceinline__ void stage_chunk(const short* src, const short* ldsbase) {
    __builtin_amdgcn_global_load_lds((const AS1 void*)src, (AS3 void*)ldsbase, 16, 0, 0);
}

// ---------------------------------------------------------------------------
// Kernel 1: linear path + bias; fully initializes d_out.
// ---------------------------------------------------------------------------
__global__ void linear_init_kernel(const float* __restrict__ x,
                                   const float* __restrict__ lin_w,
                                   const float* __restrict__ lin_b,
                                   const float* __restrict__ fin_w,
                                   const float* __restrict__ fin_b,
                                   float* __restrict__ out) {
    int wid  = threadIdx.x >> 6;
    int lane = threadIdx.x & 63;
    int b = blockIdx.x * 4 + wid;
    if (b >= Bsz) return;
    const float4* xr = (const float4*)(x + (size_t)b * Iin);
    const float4* w0 = (const float4*)(lin_w);
    const float4* w1 = (const float4*)(lin_w + Iin);
    const float4* w2 = (const float4*)(lin_w + 2 * Iin);
    float s0 = 0.f, s1 = 0.f, s2 = 0.f;
    for (int i = lane; i < Iin / 4; i += 64) {
        float4 xv = xr[i];
        float4 a0 = w0[i], a1 = w1[i], a2 = w2[i];
        s0 += xv.x * a0.x + xv.y * a0.y + xv.z * a0.z + xv.w * a0.w;
        s1 += xv.x * a1.x + xv.y * a1.y + xv.z * a1.z + xv.w * a1.w;
        s2 += xv.x * a2.x + xv.y * a2.y + xv.z * a2.z + xv.w * a2.w;
    }
    #pragma unroll
    for (int off = 1; off < 64; off <<= 1) {
        s0 += __shfl_xor(s0, off, 64);
        s1 += __shfl_xor(s1, off, 64);
        s2 += __shfl_xor(s2, off, 64);
    }
    if (lane == 0) {
        float l0 = s0 + lin_b[0], l1 = s1 + lin_b[1], l2 = s2 + lin_b[2];
        #pragma unroll
        for (int o = 0; o < 3; ++o) {
            out[b * 3 + o] = fin_b[o]
                + fin_w[(size_t)o * IF + 0] * l0
                + fin_w[(size_t)o * IF + 1] * l1
                + fin_w[(size_t)o * IF + 2] * l2;
        }
    }
}

// ---------------------------------------------------------------------------
// Kernel 2: f32 -> bf16 conversion, zero padding, + segment XOR swizzle for
// BK=32 rows: within each 4-slot (32-col) block, ws slot sub holds source
// segment sub ^ ((r>>1)&3).
// ---------------------------------------------------------------------------
__global__ void convert_kernel(const float* __restrict__ src,
                               short* __restrict__ dst,
                               int rows, int src_rows) {
    const int segs = Kp / 8;   // 776
    int total = rows * segs;
    for (int c = blockIdx.x * blockDim.x + threadIdx.x; c < total;
         c += gridDim.x * blockDim.x) {
        int r     = c / segs;
        int s_dst = c - r * segs;
        int blk   = s_dst >> 2;
        int sub   = s_dst & 3;
        int src_col = (blk << 5) + ((sub ^ ((r >> 1) & 3)) << 3);
        short8 st;
        if (r < src_rows && src_col + 8 <= Iin) {
            const float* s = src + (size_t)r * Iin + src_col;
            float4 f0 = *(const float4*)s;
            float4 f1 = *(const float4*)(s + 4);
            st = pack8(f0, f1);
        } else if (r < src_rows && src_col < Iin) {
            const float* s = src + (size_t)r * Iin + src_col;
            #pragma unroll
            for (int e = 0; e < 8; ++e) {
                float v = (src_col + e < Iin) ? s[e] : 0.f;
                st[e] = f2bf(v);
            }
        } else {
            #pragma unroll
            for (int e = 0; e < 8; ++e) st[e] = 0;
        }
        *(short8*)&dst[(size_t)r * Kp + (size_t)s_dst * 8] = st;
    }
}

// ---------------------------------------------------------------------------
// Kernel 3: 256x256 GEMM z = x @ w_int^T (bf16 MFMA) + interaction epilogue.
// 8 waves (2M x 4N), wave-tile 128x64 (M_rep=8, N_rep=4). BK=32.
// Cross-section register prefetch: af(kt+1) is ds_read during section kt and
// drains under section kt's MFMA (lgkmcnt(8) covers only the 4 fresh bf reads).
// 4-slot LDS ring, stage-ahead-3, vmcnt(4) at section start, ONE barrier/section.
// ---------------------------------------------------------------------------
__global__ __launch_bounds__(512, 2) void gemm_pf(
    const short* __restrict__ xb, const short* __restrict__ wb,
    const float* __restrict__ xf, const float* __restrict__ finw,
    float* __restrict__ out) {

    __shared__ short lsA[4][8192];   // [slot][256 rows x 32 cols]
    __shared__ short lsB[4][8192];
    __shared__ float part[256][3];

    const int tid  = threadIdx.x;
    const int lane = tid & 63;
    const int wid  = tid >> 6;       // 0..7
    const int wr   = wid >> 2;       // 0..1  (M half)
    const int wc   = wid & 3;        // 0..3  (N quarter)
    const int l15  = lane & 15;
    const int koff = (((lane >> 4) ^ ((lane >> 1) & 3)) << 3);  // swizzled k-slot

    // bijective XCD swizzle: 200 blocks = 8 XCDs x 25
    int swz = ((int)blockIdx.x & 7) * NTN + ((int)blockIdx.x >> 3);
    int tm = swz & 7;
    int tn = swz >> 3;
    int bm0 = tm << 8;
    int in0 = tn << 8;

    const int srow = lane >> 2;      // staging: row within 16-row wave chunk
    const int ssl  = lane & 3;       // staging: 16B slot within row
    const short* zptr = wb + 6176;   // 16 B of guaranteed zeros (row 0, cols>=Iin)

    f32x4 acc[8][4];
    #pragma unroll
    for (int m = 0; m < 8; ++m)
        #pragma unroll
        for (int n = 0; n < 4; ++n)
            acc[m][n] = (f32x4){0.f, 0.f, 0.f, 0.f};

    auto stageA = [&](int tk, int h) {
        int row = h * 128 + wid * 16 + srow;
        const short* src = xb + (size_t)(bm0 + row) * Kp + tk * 32 + ssl * 8;
        stage_chunk(src, &lsA[tk & 3][(h * 128 + wid * 16) * 32]);
    };
    auto stageB = [&](int tk, int h) {
        int row = h * 128 + wid * 16 + srow;
        int rg  = in0 + row;
        const short* src = (rg < NpW)
            ? wb + (size_t)rg * Kp + tk * 32 + ssl * 8 : zptr;
        stage_chunk(src, &lsB[tk & 3][(h * 128 + wid * 16) * 32]);
    };
    auto ldA = [&](int slot, int m) -> short8 {
        return *(const short8*)&lsA[slot][(wr * 128 + m * 16 + l15) * 32 + koff];
    };
    auto ldB = [&](int slot, int n) -> short8 {
        return *(const short8*)&lsB[slot][(wc * 64 + n * 16 + l15) * 32 + koff];
    };

    short8 afA[8], afB[8], bf[4];

    // prologue: stage tiles 0,1,2; read af(0) into set A
    stageA(0, 0); stageA(0, 1); stageB(0, 0); stageB(0, 1);
    stageA(1, 0); stageA(1, 1); stageB(1, 0); stageB(1, 1);
    stageA(2, 0); stageA(2, 1); stageB(2, 0); stageB(2, 1);
    asm volatile("s_waitcnt vmcnt(8)" ::: "memory");   // own tile-0 loads landed
    __builtin_amdgcn_s_barrier();                      // -> ALL tile-0 loads landed
    #pragma unroll
    for (int m = 0; m < 8; ++m) afA[m] = ldA(0, m);

// Section kt: vmcnt -> barrier -> bf(kt) -> prefetch af(kt+1) -> stage(kt+3)
//             -> lgkm(8) -> 32 MFMA on CUR set.
#define SECTION(KT, CUR, NXT, VMCLAUSE, DO_PF, DO_STAGE)                      \
    {                                                                         \
        asm volatile("s_waitcnt " VMCLAUSE ::: "memory");                     \
        __builtin_amdgcn_s_barrier();                                         \
        const int _slot = (KT) & 3;                                           \
        _Pragma("unroll")                                                     \
        for (int n = 0; n < 4; ++n) bf[n] = ldB(_slot, n);                    \
        __builtin_amdgcn_sched_barrier(0);                                    \
        if (DO_PF) {                                                          \
            const int _ns = ((KT) + 1) & 3;                                   \
            _Pragma("unroll")                                                 \
            for (int m = 0; m < 8; ++m) NXT[m] = ldA(_ns, m);                 \
        }                                                                     \
        __builtin_amdgcn_sched_barrier(0);                                    \
        if (DO_STAGE) {                                                       \
            stageA((KT) + 3, 0); stageA((KT) + 3, 1);                         \
            stageB((KT) + 3, 0); stageB((KT) + 3, 1);                         \
        }                                                                     \
        __builtin_amdgcn_sched_barrier(0);                                    \
        if (DO_PF) { asm volatile("s_waitcnt lgkmcnt(8)" ::: "memory"); }     \
        else       { asm volatile("s_waitcnt lgkmcnt(0)" ::: "memory"); }     \
        __builtin_amdgcn_sched_barrier(0);                                    \
        __builtin_amdgcn_s_setprio(1);                                        \
        _Pragma("unroll")                                                     \
        for (int m = 0; m < 8; ++m)                                           \
            _Pragma("unroll")                                                 \
            for (int n = 0; n < 4; ++n)                                       \
                acc[m][n] = __builtin_amdgcn_mfma_f32_16x16x32_bf16(          \
                    CUR[m], bf[n], acc[m][n], 0, 0, 0);                       \
        __builtin_amdgcn_s_setprio(0);                                        \
        __builtin_amdgcn_sched_barrier(0);                                    \
    }

    for (int i = 0; i < 95; ++i) {          // kt = 0..189
        int kt = 2 * i;
        SECTION(kt,     afA, afB, "vmcnt(4)", true, true);
        SECTION(kt + 1, afB, afA, "vmcnt(4)", true, true);
    }
    SECTION(190, afA, afB, "vmcnt(4)", true,  true);    // stages 193 (last)
    SECTION(191, afB, afA, "vmcnt(4)", true,  false);
    SECTION(192, afA, afB, "vmcnt(0)", true,  false);   // ensure 193 landed
    SECTION(193, afB, afA, "vmcnt(0)", false, false);
#undef SECTION

    // ---- epilogue: out[b,o] += sum_gi finw[o,3+gi] * x[b,gi] * z[b,gi]
    __syncthreads();
    for (int t = tid; t < 768; t += 512) ((float*)part)[t] = 0.f;
    __syncthreads();

    int q4 = lane >> 4;
    #pragma unroll
    for (int m = 0; m < 8; ++m) {
        #pragma unroll
        for (int r = 0; r < 4; ++r) {
            int lr = wr * 128 + m * 16 + q4 * 4 + r;   // 0..255
            int bg = bm0 + lr;
            float s0 = 0.f, s1 = 0.f, s2 = 0.f;
            #pragma unroll
            for (int n = 0; n < 4; ++n) {
                int gi = in0 + wc * 64 + n * 16 + l15;
                if (gi < Iin) {
                    float inter = acc[m][n][r] * xf[(size_t)bg * Iin + gi];
                    s0 += inter * finw[(size_t)0 * IF + 3 + gi];
                    s1 += inter * finw[(size_t)1 * IF + 3 + gi];
                    s2 += inter * finw[(size_t)2 * IF + 3 + gi];
                }
            }
            #pragma unroll
            for (int off = 1; off < 16; off <<= 1) {
                s0 += __shfl_xor(s0, off, 64);
                s1 += __shfl_xor(s1, off, 64);
                s2 += __shfl_xor(s2, off, 64);
            }
            if (l15 == 0) {
                atomicAdd(&part[lr][0], s0);
                atomicAdd(&part[lr][1], s1);
                atomicAdd(&part[lr][2], s2);
            }
        }
    }
    __syncthreads();
    for (int t = tid; t < 768; t += 512) {
        int lr = t / 3, o = t - lr * 3;
        atomicAdd(&out[(size_t)(bm0 + lr) * 3 + o], part[lr][o]);
    }
}

// ---------------------------------------------------------------------------
// Fallback (no workspace): self-staged 2-barrier kernel (mask-7 swizzle).
// ---------------------------------------------------------------------------
__global__ __launch_bounds__(256) void gemm_fallback(
    const float* __restrict__ xf, const float* __restrict__ wf,
    const float* __restrict__ finw, float* __restrict__ out) {

    __shared__ short lsA[128 * 64];
    __shared__ short lsB[128 * 64];
    __shared__ float part[128][3];

    int tid  = threadIdx.x;
    int lane = tid & 63;
    int wid  = tid >> 6;
    int wm   = wid & 1;
    int wn   = wid >> 1;

    int ntiles = (Bsz / 128) * (NpW / 128);
    int tile = (blockIdx.x & 7) * (ntiles >> 3) + (blockIdx.x >> 3);
    int tm = tile & 15;
    int tn = tile >> 4;
    int bm0 = tm << 7;
    int in0 = tn << 7;

    f32x4 acc[4][4];
    #pragma unroll
    for (int m = 0; m < 4; ++m)
        #pragma unroll
        for (int n = 0; n < 4; ++n)
            acc[m][n] = (f32x4){0.f, 0.f, 0.f, 0.f};

    for (int k0 = 0; k0 < Kp; k0 += 64) {
        #pragma unroll
        for (int it = 0; it < 4; ++it) {
            int idx = it * 256 + tid;
            int r   = idx >> 3;
            int seg = idx & 7;
            int kc  = k0 + seg * 8;
            int sd  = (seg ^ (r & 7)) << 3;
            {
                const float* s = xf + (size_t)(bm0 + r) * Iin + kc;
                short8 st;
                if (kc + 8 <= Iin) {
                    float4 f0 = *(const float4*)s;
                    float4 f1 = *(const float4*)(s + 4);
                    st = pack8(f0, f1);
                } else {
                    #pragma unroll
                    for (int e = 0; e < 8; ++e) {
                        float v = (kc + e < Iin) ? s[e] : 0.f;
                        st[e] = f2bf(v);
                    }
                }
                *(short8*)&lsA[r * 64 + sd] = st;
            }
            {
                int grow = in0 + r;
                short8 st;
                if (grow < Iin && kc + 8 <= Iin) {
                    const float* s = wf + (size_t)grow * Iin + kc;
                    float4 f0 = *(const float4*)s;
                    float4 f1 = *(const float4*)(s + 4);
                    st = pack8(f0, f1);
                } else if (grow < Iin) {
                    const float* s = wf + (size_t)grow * Iin + kc;
                    #pragma unroll
                    for (int e = 0; e < 8; ++e) {
                        float v = (kc + e < Iin) ? s[e] : 0.f;
                        st[e] = f2bf(v);
                    }
                } else {
                    #pragma unroll
                    for (int e = 0; e < 8; ++e) st[e] = 0;
                }
                *(short8*)&lsB[r * 64 + sd] = st;
            }
        }
        __syncthreads();

        #pragma unroll
        for (int kk = 0; kk < 2; ++kk) {
            int q = (kk << 2) + (lane >> 4);
            short8 af[4], bfr[4];
            #pragma unroll
            for (int m = 0; m < 4; ++m) {
                int R = wm * 64 + m * 16 + (lane & 15);
                af[m] = *(const short8*)&lsA[R * 64 + ((q ^ (R & 7)) << 3)];
            }
            #pragma unroll
            for (int n = 0; n < 4; ++n) {
                int R = wn * 64 + n * 16 + (lane & 15);
                bfr[n] = *(const short8*)&lsB[R * 64 + ((q ^ (R & 7)) << 3)];
            }
            #pragma unroll
            for (int m = 0; m < 4; ++m)
                #pragma unroll
                for (int n = 0; n < 4; ++n)
                    acc[m][n] = __builtin_amdgcn_mfma_f32_16x16x32_bf16(
                        af[m], bfr[n], acc[m][n], 0, 0, 0);
        }
        __syncthreads();
    }

    for (int t = tid; t < 384; t += 256) ((float*)part)[t] = 0.f;
    __syncthreads();

    #pragma unroll
    for (int m = 0; m < 4; ++m) {
        int rowbase = bm0 + wm * 64 + m * 16 + ((lane >> 4) << 2);
        #pragma unroll
        for (int r = 0; r < 4; ++r) {
            int b = rowbase + r;
            float s0 = 0.f, s1 = 0.f, s2 = 0.f;
            #pragma unroll
            for (int n = 0; n < 4; ++n) {
                int gi = in0 + wn * 64 + n * 16 + (lane & 15);
                if (gi < Iin) {
                    float inter = acc[m][n][r] * xf[(size_t)b * Iin + gi];
                    s0 += inter * finw[(size_t)0 * IF + 3 + gi];
                    s1 += inter * finw[(size_t)1 * IF + 3 + gi];
                    s2 += inter * finw[(size_t)2 * IF + 3 + gi];
                }
            }
            #pragma unroll
            for (int off = 1; off < 16; off <<= 1) {
                s0 += __shfl_xor(s0, off, 64);
                s1 += __shfl_xor(s1, off, 64);
                s2 += __shfl_xor(s2, off, 64);
            }
            if ((lane & 15) == 0) {
                int lr = b - bm0;
                atomicAdd(&part[lr][0], s0);
                atomicAdd(&part[lr][1], s1);
                atomicAdd(&part[lr][2], s2);
            }
        }
    }
    __syncthreads();
    for (int t = tid; t < 384; t += 256) {
        int lr = t / 3, o = t - lr * 3;
        atomicAdd(&out[(size_t)(bm0 + lr) * 3 + o], part[lr][o]);
    }
}

// ---------------------------------------------------------------------------
extern "C" void kernel_launch(void* const* d_in, const int* in_sizes, int n_in,
                              void* d_out, int out_size, void* d_ws, size_t ws_size,
                              hipStream_t stream) {
    const float* x     = (const float*)d_in[0];
    const float* lin_w = (const float*)d_in[1];
    const float* lin_b = (const float*)d_in[2];
    const float* w_int = (const float*)d_in[3];
    const float* fin_w = (const float*)d_in[4];
    const float* fin_b = (const float*)d_in[5];
    float* out = (float*)d_out;

    linear_init_kernel<<<Bsz / 4, 256, 0, stream>>>(x, lin_w, lin_b, fin_w, fin_b, out);

    const size_t xb_elems = (size_t)Bsz * Kp;    // 12,713,984
    const size_t wb_elems = (size_t)NpW * Kp;    // 38,936,576
    const size_t need = (xb_elems + wb_elems) * sizeof(short);   // 103.3 MB

    if (ws_size >= need) {
        short* xb = (short*)d_ws;
        short* wb = xb + xb_elems;
        convert_kernel<<<2048, 256, 0, stream>>>(x, xb, Bsz, Bsz);
        convert_kernel<<<2048, 256, 0, stream>>>(w_int, wb, NpW, Iin);
        gemm_pf<<<MT * NTN, 512, 0, stream>>>(xb, wb, x, fin_w, out);
    } else {
        const int ntiles = (Bsz / 128) * (NpW / 128);
        gemm_fallback<<<ntiles, 256, 0, stream>>>(x, w_int, fin_w, out);
    }
}